// Round 10
// baseline (186.738 us; speedup 1.0000x reference)
//
#include <hip/hip_runtime.h>
#include <cstdint>
#include <cstddef>

#define DIM 128
#define HEADS 4

typedef __attribute__((ext_vector_type(8))) short bf16x8;
typedef __attribute__((ext_vector_type(4))) float f32x4;

__device__ __forceinline__ ushort f2bf(float x) {
    union { float f; uint32_t u; } v; v.f = x;
    uint32_t r = v.u + 0x7FFFu + ((v.u >> 16) & 1u);   // RNE
    return (ushort)(r >> 16);
}
__device__ __forceinline__ float bf2f(ushort h) {
    union { uint32_t u; float f; } v; v.u = ((uint32_t)h) << 16; return v.f;
}

// ---------------------------------------------------------------------------
// prep: fused wtrans (blocks 0..191) + count_degree (blocks 192..)
// wtrans: W[k][col] f32 -> Wt in MFMA-FRAGMENT order, bf16 hi/lo:
//   t = ((w*4 + c)*8 + g)*512 + ln*8 + j
//   col = g*16 + (ln&15),  k = c*32 + (ln>>4)*8 + j
// -> a wave's B-fragment load is 64 lanes x 16B CONTIGUOUS from global.
// ---------------------------------------------------------------------------
__global__ __launch_bounds__(256)
void prep(const float* __restrict__ qW, const float* __restrict__ kW,
          const float* __restrict__ vW,
          ushort* __restrict__ WtHi, ushort* __restrict__ WtLo,
          const int* __restrict__ rows, int* __restrict__ degree, int E)
{
    int b = blockIdx.x;
    if (b < 192) {
        int t = b * 256 + threadIdx.x;           // 0..49151
        int j  = t & 7;
        int ln = (t >> 3) & 63;
        int g  = (t >> 9) & 7;
        int c  = (t >> 12) & 3;
        int w  = t >> 14;
        const float* W = (w == 0) ? qW : (w == 1) ? kW : vW;
        int col = g * 16 + (ln & 15);
        int k   = c * 32 + ((ln >> 4) << 3) + j;
        float x = W[k * DIM + col];
        ushort hi = f2bf(x);
        ushort lo = f2bf(x - bf2f(hi));
        WtHi[t] = hi;
        WtLo[t] = lo;
    } else {
        int e = (b - 192) * 256 + threadIdx.x;
        if (e < E) atomicAdd(&degree[rows[e]], 1);
    }
}

// ---------------------------------------------------------------------------
// qkv_fused v5: NO LDS, NO barriers. 256 thr = 4 waves (2M x 2N); block =
// 64 rows x 64 cols (blockIdx.y = col half). Each wave loads its own A
// fragments DIRECTLY from emb (16 rows x 64B contiguous runs per load pair),
// converts f32->bf16 hi/lo in registers (VALU co-issues with MFMA), and loads
// B fragments direct from pre-swizzled global Wt (L2-resident, 1KB/wave
// coalesced). Waves free-run -> latency hidden by occupancy + pipelining.
// MFMA per-acc term order identical to R5 (k ascending; hh, lh, hl per
// 32-k slice) and identical f2bf conversions -> bit-exact outputs.
// Epilogue: Q -> Qb[r][128]; K,V interleaved -> KVb[r][256].
// ---------------------------------------------------------------------------
__global__ __launch_bounds__(256)
void qkv_fused(const float* __restrict__ emb,
               const ushort* __restrict__ WtHi, const ushort* __restrict__ WtLo,
               ushort* __restrict__ Qb, ushort* __restrict__ KVb, int N)
{
    const int tid = threadIdx.x;
    const int wv = tid >> 6;
    const int ln = tid & 63;
    const int l15 = ln & 15;
    const int l4 = ln >> 4;
    const int wm = wv >> 1;             // wave row group (32 rows)
    const int wn = wv & 1;              // wave col group (32 cols)
    const int m0 = blockIdx.x * 64;
    const int gbase = blockIdx.y * 4;   // global col-group base (16-col units)

    f32x4 acc[3][2][2] = {};            // [wsel][fr][n]

    for (int c = 0; c < 4; c++) {       // k chunk: k = c*32 .. +32
        // ---- A frags: row = m0+wm*32+fr*16+l15, k = c*32+l4*8..+8 ----
        bf16x8 ah[2], al[2];
#pragma unroll
        for (int fr = 0; fr < 2; fr++) {
            int row = m0 + wm * 32 + fr * 16 + l15;
            float4 a0 = make_float4(0.f, 0.f, 0.f, 0.f);
            float4 a1 = a0;
            if (row < N) {
                const float* src = emb + (size_t)row * DIM + c * 32 + l4 * 8;
                a0 = *(const float4*)(src);
                a1 = *(const float4*)(src + 4);
            }
            ushort h0, h1, h2, h3, h4, h5, h6, h7;
            h0 = f2bf(a0.x); h1 = f2bf(a0.y); h2 = f2bf(a0.z); h3 = f2bf(a0.w);
            h4 = f2bf(a1.x); h5 = f2bf(a1.y); h6 = f2bf(a1.z); h7 = f2bf(a1.w);
            bf16x8 h, l;
            h[0] = (short)h0; l[0] = (short)f2bf(a0.x - bf2f(h0));
            h[1] = (short)h1; l[1] = (short)f2bf(a0.y - bf2f(h1));
            h[2] = (short)h2; l[2] = (short)f2bf(a0.z - bf2f(h2));
            h[3] = (short)h3; l[3] = (short)f2bf(a0.w - bf2f(h3));
            h[4] = (short)h4; l[4] = (short)f2bf(a1.x - bf2f(h4));
            h[5] = (short)h5; l[5] = (short)f2bf(a1.y - bf2f(h5));
            h[6] = (short)h6; l[6] = (short)f2bf(a1.z - bf2f(h6));
            h[7] = (short)h7; l[7] = (short)f2bf(a1.w - bf2f(h7));
            ah[fr] = h;
            al[fr] = l;
        }
        // ---- B frags direct from pre-swizzled global (L2-resident) ----
#pragma unroll
        for (int w = 0; w < 3; w++) {
#pragma unroll
            for (int n = 0; n < 2; n++) {
                size_t goff = ((size_t)((w * 4 + c) * 8 + gbase + wn * 2 + n)) * 512
                            + (size_t)ln * 8;
                bf16x8 bh = *(const bf16x8*)(WtHi + goff);
                bf16x8 bl = *(const bf16x8*)(WtLo + goff);
#pragma unroll
                for (int fr = 0; fr < 2; fr++) {
                    acc[w][fr][n] = __builtin_amdgcn_mfma_f32_16x16x32_bf16(ah[fr], bh, acc[w][fr][n], 0, 0, 0);
                    acc[w][fr][n] = __builtin_amdgcn_mfma_f32_16x16x32_bf16(al[fr], bh, acc[w][fr][n], 0, 0, 0);
                    acc[w][fr][n] = __builtin_amdgcn_mfma_f32_16x16x32_bf16(ah[fr], bl, acc[w][fr][n], 0, 0, 0);
                }
            }
        }
    }

    // ---- epilogue: C/D layout col=lane&15, row=(lane>>4)*4+j ----
#pragma unroll
    for (int w = 0; w < 3; w++) {
#pragma unroll
        for (int fr = 0; fr < 2; fr++) {
            int rbase = m0 + wm * 32 + fr * 16 + l4 * 4;
#pragma unroll
            for (int n = 0; n < 2; n++) {
                int col = blockIdx.y * 64 + wn * 32 + n * 16 + l15;
#pragma unroll
                for (int j = 0; j < 4; j++) {
                    int r = rbase + j;
                    if (r < N) {
                        ushort val = f2bf(acc[w][fr][n][j]);
                        if (w == 0) Qb[(size_t)r * DIM + col] = val;
                        else        KVb[(size_t)r * 256 + (w - 1) * 128 + col] = val;
                    }
                }
            }
        }
    }
}

// ---------------------------------------------------------------------------
// CSR build: exclusive scan of degree -> rowPtr, then permutation fill.
// ---------------------------------------------------------------------------
__global__ __launch_bounds__(256)
void scanA(const int* __restrict__ degree, int* __restrict__ rowPtr,
           int* __restrict__ blockSums, int N)
{
    __shared__ int s[256];
    const int tid = threadIdx.x;
    const int base = blockIdx.x * 1024 + tid * 4;
    int d[4];
    int tsum = 0;
#pragma unroll
    for (int i = 0; i < 4; i++) {
        d[i] = (base + i < N) ? degree[base + i] : 0;
        tsum += d[i];
    }
    s[tid] = tsum;
    __syncthreads();
    for (int off = 1; off < 256; off <<= 1) {
        int v = (tid >= off) ? s[tid - off] : 0;
        __syncthreads();
        s[tid] += v;
        __syncthreads();
    }
    if (tid == 255) blockSums[blockIdx.x] = s[255];   // raw block total
    int running = s[tid] - tsum;
#pragma unroll
    for (int i = 0; i < 4; i++) {
        if (base + i < N) rowPtr[base + i] = running;
        running += d[i];
    }
}

// scanC (scanB merged): each block reduces raw blockSums[0..bid) itself
// (nb <= 128), adds offset, copies into cursor, sets rowPtr[N] = E.
__global__ __launch_bounds__(256)
void scanC(int* __restrict__ rowPtr, const int* __restrict__ blockSums,
           int* __restrict__ cursor, int N, int E, int nb)
{
    __shared__ int s[128];
    const int tid = threadIdx.x;
    const int bid = blockIdx.x;
    if (tid < 128) {
        int lim = (bid < nb) ? bid : nb;
        s[tid] = (tid < lim) ? blockSums[tid] : 0;
    }
    __syncthreads();
    // tree-reduce 128 -> 1
    for (int off = 64; off > 0; off >>= 1) {
        if (tid < off) s[tid] += s[tid + off];
        __syncthreads();
    }
    const int off = s[0];
    const int base = bid * 1024 + tid * 4;
#pragma unroll
    for (int i = 0; i < 4; i++) {
        int idx = base + i;
        if (idx < N) {
            int v = rowPtr[idx] + off;
            rowPtr[idx] = v;
            cursor[idx] = v;
        }
    }
    if (bid == 0 && tid == 0) rowPtr[N] = E;
}

__global__ __launch_bounds__(256)
void fill_perm(const int* __restrict__ rows, const int* __restrict__ cols,
               int* __restrict__ cursor, int* __restrict__ perm,
               int* __restrict__ colsCSR, int E)
{
    int e = blockIdx.x * 256 + threadIdx.x;
    if (e >= E) return;
    int pos = atomicAdd(&cursor[rows[e]], 1);
    perm[pos] = e;
    colsCSR[pos] = cols[e];
}

// ---------------------------------------------------------------------------
// csr_fused: 16 lanes per node (8 dims/lane), 4 nodes per wave. Edge loop
// UNROLL-4 (avg degree = 4): up to 16 independent gathers in flight/node.
// Per-edge accumulation order sequential in p -> bit-exact vs unroll-2.
// ---------------------------------------------------------------------------
__global__ __launch_bounds__(256)
void csr_fused(const ushort* __restrict__ Qb, const ushort* __restrict__ KVb,
               const int* __restrict__ rowPtr, const int* __restrict__ perm,
               const int* __restrict__ colsCSR,
               float* __restrict__ attBuf, float* __restrict__ invNorm,
               float* __restrict__ out, int N)
{
    int t = blockIdx.x * 256 + threadIdx.x;
    int node = t >> 4;
    int lane = t & 15;                  // 16 lanes/node
    if (node >= N) return;

    const int start = rowPtr[node];
    const int end   = rowPtr[node + 1];
    const int h = lane >> 2;            // head (4 lanes each)

    const ushort* qp = Qb + (size_t)node * DIM + lane * 8;
    ushort4 qu0 = *(const ushort4*)(qp);
    ushort4 qu1 = *(const ushort4*)(qp + 4);
    float q[8] = {bf2f(qu0.x), bf2f(qu0.y), bf2f(qu0.z), bf2f(qu0.w),
                  bf2f(qu1.x), bf2f(qu1.y), bf2f(qu1.z), bf2f(qu1.w)};

    float norm = 0.f;
    float acc[8] = {0.f, 0.f, 0.f, 0.f, 0.f, 0.f, 0.f, 0.f};

    int p = start;
    for (; p + 4 <= end; p += 4) {
        int cc[4], ee[4];
#pragma unroll
        for (int u = 0; u < 4; u++) { cc[u] = colsCSR[p + u]; ee[u] = perm[p + u]; }
        ushort4 ka[4], kb[4], va[4], vb[4];
#pragma unroll
        for (int u = 0; u < 4; u++) {
            const ushort* kv = KVb + (size_t)cc[u] * 256 + lane * 8;
            ka[u] = *(const ushort4*)(kv);
            kb[u] = *(const ushort4*)(kv + 4);
            va[u] = *(const ushort4*)(kv + 128);
            vb[u] = *(const ushort4*)(kv + 132);
        }
        float d[4];
#pragma unroll
        for (int u = 0; u < 4; u++) {
            d[u] = bf2f(ka[u].x) * q[0] + bf2f(ka[u].y) * q[1]
                 + bf2f(ka[u].z) * q[2] + bf2f(ka[u].w) * q[3]
                 + bf2f(kb[u].x) * q[4] + bf2f(kb[u].y) * q[5]
                 + bf2f(kb[u].z) * q[6] + bf2f(kb[u].w) * q[7];
        }
#pragma unroll
        for (int u = 0; u < 4; u++) d[u] += __shfl_xor(d[u], 1, 64);
#pragma unroll
        for (int u = 0; u < 4; u++) d[u] += __shfl_xor(d[u], 2, 64);
        float ex[4];
#pragma unroll
        for (int u = 0; u < 4; u++) {
            float dd = fminf(fmaxf(d[u], -10.f), 10.f);
            ex[u] = __expf(dd);
        }
        if ((lane & 3) == 0) {
#pragma unroll
            for (int u = 0; u < 4; u++)
                attBuf[(size_t)ee[u] * HEADS + h] = ex[u];
        }
#pragma unroll
        for (int u = 0; u < 4; u++) {
            norm += ex[u];
            acc[0] += ex[u] * bf2f(va[u].x);
            acc[1] += ex[u] * bf2f(va[u].y);
            acc[2] += ex[u] * bf2f(va[u].z);
            acc[3] += ex[u] * bf2f(va[u].w);
            acc[4] += ex[u] * bf2f(vb[u].x);
            acc[5] += ex[u] * bf2f(vb[u].y);
            acc[6] += ex[u] * bf2f(vb[u].z);
            acc[7] += ex[u] * bf2f(vb[u].w);
        }
    }
    for (; p < end; p++) {
        int c = colsCSR[p];
        int e = perm[p];
        const ushort* kv = KVb + (size_t)c * 256 + lane * 8;
        ushort4 ka = *(const ushort4*)(kv);
        ushort4 kb = *(const ushort4*)(kv + 4);
        ushort4 va = *(const ushort4*)(kv + 128);
        ushort4 vb = *(const ushort4*)(kv + 132);
        float d = bf2f(ka.x) * q[0] + bf2f(ka.y) * q[1]
                + bf2f(ka.z) * q[2] + bf2f(ka.w) * q[3]
                + bf2f(kb.x) * q[4] + bf2f(kb.y) * q[5]
                + bf2f(kb.z) * q[6] + bf2f(kb.w) * q[7];
        d += __shfl_xor(d, 1, 64);
        d += __shfl_xor(d, 2, 64);
        d = fminf(fmaxf(d, -10.f), 10.f);
        float ex = __expf(d);
        if ((lane & 3) == 0) attBuf[(size_t)e * HEADS + h] = ex;
        norm += ex;
        acc[0] += ex * bf2f(va.x);
        acc[1] += ex * bf2f(va.y);
        acc[2] += ex * bf2f(va.z);
        acc[3] += ex * bf2f(va.w);
        acc[4] += ex * bf2f(vb.x);
        acc[5] += ex * bf2f(vb.y);
        acc[6] += ex * bf2f(vb.z);
        acc[7] += ex * bf2f(vb.w);
    }

    float inv = 1.f / (norm + 1e-8f);
    if ((lane & 3) == 0) invNorm[(size_t)node * HEADS + h] = inv;
    float* op = out + (size_t)node * DIM + lane * 8;
    *(float4*)(op)     = make_float4(acc[0] * inv, acc[1] * inv,
                                     acc[2] * inv, acc[3] * inv);
    *(float4*)(op + 4) = make_float4(acc[4] * inv, acc[5] * inv,
                                     acc[6] * inv, acc[7] * inv);
}

// ---------------------------------------------------------------------------
// att_scale: attBuf[e][h] *= invNorm[rows[e]][h]   (finishes softmax)
// ---------------------------------------------------------------------------
__global__ __launch_bounds__(256)
void att_scale(float* __restrict__ attBuf, const float* __restrict__ invNorm,
               const int* __restrict__ rows, int E4)
{
    int t = blockIdx.x * 256 + threadIdx.x;
    if (t >= E4) return;
    int e = t >> 2;
    attBuf[t] *= invNorm[(size_t)rows[e] * 4 + (t & 3)];
}

// ---------------------------------------------------------------------------
// kernel_launch
// ws: Qb bf16 [N*128] | KVb bf16 [N*256] | WtHi,WtLo bf16 [3*128*128]*2
//     | invNorm f32 [N*4] | rowPtr[N+1] | blockSums[128] | cursor[N]
//     | perm[E] | colsCSR[E] | degree[N]
// ---------------------------------------------------------------------------
extern "C" void kernel_launch(void* const* d_in, const int* in_sizes, int n_in,
                              void* d_out, int out_size, void* d_ws, size_t ws_size,
                              hipStream_t stream)
{
    const float* emb  = (const float*)d_in[0];
    const float* qW   = (const float*)d_in[1];
    const float* kW   = (const float*)d_in[2];
    const float* vW   = (const float*)d_in[3];
    const int*   rows = (const int*)d_in[4];
    const int*   cols = (const int*)d_in[5];

    const int N = in_sizes[0] / DIM;
    const int E = in_sizes[4];

    float* dout   = (float*)d_out;
    float* outMat = dout;                        // [N,128]
    float* attBuf = dout + (size_t)N * DIM;      // [E,4]

    ushort* Qb   = (ushort*)d_ws;
    ushort* KVb  = Qb + (size_t)N * DIM;
    ushort* WtHi = KVb + (size_t)N * 256;
    ushort* WtLo = WtHi + 3 * DIM * DIM;
    float* invNorm = (float*)(WtLo + 3 * DIM * DIM);
    int* rowPtr    = (int*)(invNorm + (size_t)N * HEADS);
    int* blockSums = rowPtr + (N + 1);
    int* cursor    = blockSums + 128;
    int* perm      = cursor + N;
    int* colsCSR   = perm + E;
    int* degree    = colsCSR + E;

    hipMemsetAsync(degree, 0, (size_t)N * sizeof(int), stream);

    int eblocks = (E + 255) / 256;
    prep<<<192 + eblocks, 256, 0, stream>>>(qW, kW, vW, WtHi, WtLo,
                                            rows, degree, E);

    dim3 ggrid((N + 63) / 64, 2);
    qkv_fused<<<ggrid, 256, 0, stream>>>(emb, WtHi, WtLo, Qb, KVb, N);

    int nb = (N + 1023) / 1024;
    scanA<<<nb, 256, 0, stream>>>(degree, rowPtr, blockSums, N);
    scanC<<<nb, 256, 0, stream>>>(rowPtr, blockSums, cursor, N, E, nb);

    fill_perm<<<eblocks, 256, 0, stream>>>(rows, cols, cursor, perm, colsCSR, E);

    int gblocks = (N * 16 + 255) / 256;
    csr_fused<<<gblocks, 256, 0, stream>>>(Qb, KVb, rowPtr, perm, colsCSR,
                                           attBuf, invNorm, outMat, N);

    int sblocks = (E * HEADS + 255) / 256;
    att_scale<<<sblocks, 256, 0, stream>>>(attBuf, invNorm, rows, E * HEADS);
}